// Round 13
// baseline (250.772 us; speedup 1.0000x reference)
//
#include <hip/hip_runtime.h>

typedef unsigned short u16;
typedef __attribute__((ext_vector_type(8))) short s8v;   // 8 x bf16 (4 VGPR)
typedef __attribute__((ext_vector_type(4))) float f4v;   // MFMA accum

#define MFMA16(a, b, c) __builtin_amdgcn_mfma_f32_16x16x32_bf16(a, b, c, 0, 0, 0)

#define TSEQ 2048
#define NTOK 4096          // B*T
#define HEADS 32           // H*B
#define HB_ELEMS 131072    // T*dh elems per head block

__device__ __forceinline__ unsigned cvt_pk(float lo, float hi) {
  unsigned r;
  asm("v_cvt_pk_bf16_f32 %0, %1, %2" : "=v"(r) : "v"(lo), "v"(hi));
  return r;
}

__device__ __forceinline__ void gl_lds16(const u16* g, u16* l) {
  __builtin_amdgcn_global_load_lds(
      (const __attribute__((address_space(1))) void*)g,
      (__attribute__((address_space(3))) void*)l, 16, 0, 0);
}

// ---------------- projection GEMM: C = A(4096x1024) * W(1024x1024)^T + bias ----
// fp32->bf16 conversion FUSED into staging (reg-staged: global f32 -> cvt_pk
// -> ds_write_b128). Eliminates the separate cvt pass over q/k/v/weights.
// Epilogue bounces output through LDS for coalesced 16B stores.
__launch_bounds__(256, 2)
__global__ void proj_gemm(const float* __restrict__ qf, const float* __restrict__ kf,
                          const float* __restrict__ vf, const float* __restrict__ wqf,
                          const float* __restrict__ wkf, const float* __restrict__ wvf,
                          const float* __restrict__ bqp, const float* __restrict__ bkp,
                          const float* __restrict__ bvp, u16* __restrict__ Call) {
  const int z = blockIdx.z;
  const float* A = (z == 0) ? qf : ((z == 1) ? kf : vf);
  const float* W = (z == 0) ? wqf : ((z == 1) ? wkf : wvf);
  u16* C = Call + (size_t)z * 4194304;
  const float* bias = (z == 0) ? bqp : ((z == 1) ? bkp : bvp);

  __shared__ __align__(16) u16 SH[17408];   // As[0..8K) Bs[8K..16K); T[128][136]
  u16* As = SH;
  u16* Bs = SH + 8192;

  const int tid = threadIdx.x;
  const int w = tid >> 6, lane = tid & 63, g = lane >> 4, l = lane & 15;
  const int wr = w >> 1, wc = w & 1;
  const int tr = blockIdx.y * 128, tc = blockIdx.x * 128;

  const int srow = tid >> 3;        // 0..31  (staging row within 32-row chunk)
  const int scol = (tid & 7) * 8;   // elem col within 64

  f4v acc[4][4] = {};

  for (int kt = 0; kt < 1024; kt += 64) {
#pragma unroll
    for (int c4 = 0; c4 < 4; ++c4) {
      const float* ar = A + (size_t)(tr + c4 * 32 + srow) * 1024 + kt + scol;
      const float* wr_ = W + (size_t)(tc + c4 * 32 + srow) * 1024 + kt + scol;
      float4 a0 = *(const float4*)ar;
      float4 a1 = *(const float4*)(ar + 4);
      float4 b0 = *(const float4*)wr_;
      float4 b1 = *(const float4*)(wr_ + 4);
      union { unsigned u[4]; s8v s; } ua, ub;
      ua.u[0] = cvt_pk(a0.x, a0.y); ua.u[1] = cvt_pk(a0.z, a0.w);
      ua.u[2] = cvt_pk(a1.x, a1.y); ua.u[3] = cvt_pk(a1.z, a1.w);
      ub.u[0] = cvt_pk(b0.x, b0.y); ub.u[1] = cvt_pk(b0.z, b0.w);
      ub.u[2] = cvt_pk(b1.x, b1.y); ub.u[3] = cvt_pk(b1.z, b1.w);
      *(s8v*)(As + c4 * 2048 + tid * 8) = ua.s;
      *(s8v*)(Bs + c4 * 2048 + tid * 8) = ub.s;
    }
    __syncthreads();
#pragma unroll
    for (int ks = 0; ks < 2; ++ks) {
      s8v a[4], bb[4];
#pragma unroll
      for (int m = 0; m < 4; ++m)
        a[m] = *(const s8v*)(As + (wr * 64 + m * 16 + l) * 64 + ks * 32 + g * 8);
#pragma unroll
      for (int n = 0; n < 4; ++n)
        bb[n] = *(const s8v*)(Bs + (wc * 64 + n * 16 + l) * 64 + ks * 32 + g * 8);
#pragma unroll
      for (int m = 0; m < 4; ++m)
#pragma unroll
        for (int n = 0; n < 4; ++n)
          acc[m][n] = MFMA16(a[m], bb[n], acc[m][n]);
    }
    __syncthreads();
  }
  // ---- epilogue: bias + bf16 pack into LDS tile T[t 128][d 136], then
  // coalesced 16B global stores. (Loop's trailing barrier makes SH reuse safe.)
  u16* T = SH;
#pragma unroll
  for (int m = 0; m < 4; ++m)
#pragma unroll
    for (int n = 0; n < 4; ++n) {
      int d = wc * 64 + n * 16 + l;
      float bv = bias[tc + d];
      unsigned c01 = cvt_pk(acc[m][n][0] + bv, acc[m][n][1] + bv);
      unsigned c23 = cvt_pk(acc[m][n][2] + bv, acc[m][n][3] + bv);
      int t0 = wr * 64 + m * 16 + g * 4;
      T[(t0 + 0) * 136 + d] = (u16)c01;
      T[(t0 + 1) * 136 + d] = (u16)(c01 >> 16);
      T[(t0 + 2) * 136 + d] = (u16)c23;
      T[(t0 + 3) * 136 + d] = (u16)(c23 >> 16);
    }
  __syncthreads();
#pragma unroll
  for (int it = 0; it < 8; ++it) {
    int t = it * 16 + (tid >> 4);
    int c8 = (tid & 15) * 8;
    *(s8v*)(C + (size_t)(tr + t) * 1024 + tc + c8) = *(const s8v*)&T[t * 136 + c8];
  }
}

// ---------------- per-head V transpose: vT[hb][d][t] = vp[hb][t][d] ----------
__global__ void vtrans(const u16* __restrict__ vp, u16* __restrict__ vT) {
  const int hb = blockIdx.y;
  const int t0 = blockIdx.x * 64;
  const int tid = threadIdx.x;
  __shared__ u16 tl[64][65];
  const u16* vph = vp + (size_t)hb * HB_ELEMS;
  u16* vth = vT + (size_t)hb * HB_ELEMS;
#pragma unroll
  for (int it = 0; it < 4; ++it) {
    int i = (tid + it * 256) * 4;
    int r = i >> 6, c = i & 63;
    *(ushort4*)&tl[r][c] = *(const ushort4*)(vph + (size_t)(t0 + r) * 64 + c);
  }
  __syncthreads();
#pragma unroll
  for (int it = 0; it < 4; ++it) {
    int i = (tid + it * 256) * 4;
    int d = i >> 6, j = i & 63;
    ushort4 o;
    o.x = tl[j + 0][d]; o.y = tl[j + 1][d]; o.z = tl[j + 2][d]; o.w = tl[j + 3][d];
    *(ushort4*)(vth + (size_t)d * TSEQ + t0 + j) = o;
  }
}

// ---------------- fused attention: LDS-staged K/V, swapped-QK^T --------------
// grid: 1024 blocks (32 qtiles x 32 heads, XCD-swizzled); 4 waves x 16 q-rows.
// Pass 1: 256-key rounds. Pass 2: 64-key rounds; P tile kept in fp32 LDS and
// flushed by a dedicated store phase (16 rows x 256B contiguous per instr).
// Column-window rotation spreads concurrent blocks across HBM channels.
__launch_bounds__(256, 4)
__global__ void attn_fused(const u16* __restrict__ qp, const u16* __restrict__ kp,
                           const u16* __restrict__ vT, float* __restrict__ attn,
                           float* __restrict__ ctx) {
  // XCD-bijective swizzle: all 32 q-tiles of a head share (hw & 7) -> same XCD
  const int hw = blockIdx.x + (blockIdx.y << 5);
  const int hb = (hw & 7) + ((hw >> 8) << 3);
  const int qt = (hw >> 3) & 31;

  const int tid = threadIdx.x;
  const int w = tid >> 6, lane = tid & 63, g = lane >> 4, l = lane & 15;
  const int lx = l & 7;

  const u16* qh = qp + (size_t)hb * HB_ELEMS;
  const u16* kh = kp + (size_t)hb * HB_ELEMS;
  const u16* vh = vT + (size_t)hb * HB_ELEMS;

  // pass1: K[256][64] (32KB). pass2: Kl 8KB | Vl 8KB | Pf[64][72] f32 18KB.
  __shared__ __align__(16) u16 SH[17408];

  const int row0 = qt * 64 + w * 16;              // wave's 16 q-rows
  const float scale = 0.125f;                     // dh^-0.5

  // staging geometry: thread t covers rows (t>>3)+{0,32,..}, 16B chunk t&7
  const int srow = tid >> 3;
  const int swc = ((tid & 7) ^ (srow & 7)) * 8;   // swizzled source col (elems)

  // Q as B-operand fragment: lane (g,l) holds Q[row0+l][ks*32+g*8 .. +8)
  s8v qf0 = *(const s8v*)(qh + (size_t)(row0 + l) * 64 + g * 8);
  s8v qf1 = *(const s8v*)(qh + (size_t)(row0 + l) * 64 + 32 + g * 8);

  // ---- pass 1: row sums of exp(score); swapped mfma(K,Q) => C col = q-row l
  float sum = 0.0f;
  for (int kt4 = 0; kt4 < 8; ++kt4) {
    const int c0 = kt4 * 256;
#pragma unroll
    for (int c8 = 0; c8 < 8; ++c8)
      gl_lds16(kh + (size_t)(c0 + c8 * 32 + srow) * 64 + swc,
               SH + c8 * 2048 + tid * 8);
    __syncthreads();
#pragma unroll
    for (int q4 = 0; q4 < 4; ++q4) {
#pragma unroll
      for (int n = 0; n < 4; ++n) {
        const u16* kr = SH + q4 * 4096 + (n * 16 + l) * 64;
        s8v b0 = *(const s8v*)(kr + (g ^ lx) * 8);
        s8v b1 = *(const s8v*)(kr + ((4 + g) ^ lx) * 8);
        f4v s = {};
        s = MFMA16(b0, qf0, s);
        s = MFMA16(b1, qf1, s);
        sum += __expf(s[0] * scale) + __expf(s[1] * scale)
             + __expf(s[2] * scale) + __expf(s[3] * scale);
      }
    }
    __syncthreads();
  }
  // reduce across the 4 g-groups holding the same q-row l
  sum += __shfl_xor(sum, 16);
  sum += __shfl_xor(sum, 32);
  const float inv = 1.0f / sum;

  // ---- pass 2: recompute, P -> fp32 LDS, PV, then coalesced store phase ----
  u16* Kl = SH;                       // [64][64] bf16 swizzled (8 KB)
  u16* Vl = SH + 4096;                // [64][64] bf16 swizzled (8 KB)
  float* Pf = (float*)(SH + 8192);    // [64][72] f32 P tile (18 KB)

  f4v cacc[4] = {};
  float* attn_h = attn + (size_t)hb * TSEQ * TSEQ;
  const int kt0 = (qt + ((hw >> 8) << 3)) & 31;   // column-window rotation
  const int prow = w * 16 + l;                    // this lane's P row
  const int st_r = tid >> 4;                      // store-phase row within 16
  const int st_c = (tid & 15) * 4;                // store-phase float col
  for (int i = 0; i < 32; ++i) {
    const int kt = (i + kt0) & 31;
    const int col0 = kt * 64;
    gl_lds16(kh + (size_t)(col0 + srow) * 64 + swc, Kl + tid * 8);
    gl_lds16(kh + (size_t)(col0 + 32 + srow) * 64 + swc, Kl + 2048 + tid * 8);
    gl_lds16(vh + (size_t)srow * TSEQ + col0 + swc, Vl + tid * 8);
    gl_lds16(vh + (size_t)(srow + 32) * TSEQ + col0 + swc, Vl + 2048 + tid * 8);
    __syncthreads();   // A: stage complete; prev store-phase Pf reads done
#pragma unroll
    for (int n = 0; n < 4; ++n) {
      const u16* kr = Kl + (n * 16 + l) * 64;
      s8v b0 = *(const s8v*)(kr + (g ^ lx) * 8);
      s8v b1 = *(const s8v*)(kr + ((4 + g) ^ lx) * 8);
      f4v s = {};
      s = MFMA16(b0, qf0, s);
      s = MFMA16(b1, qf1, s);
      f4v p;
#pragma unroll
      for (int r = 0; r < 4; ++r) p[r] = __expf(s[r] * scale) * inv;
      // P[q-row l][keys n*16+g*4 .. +4) for this wave
      *(f4v*)&Pf[prow * 72 + n * 16 + g * 4] = p;
    }
    // PV for this 64-key tile: read wave-local P rows, pack bf16 on the fly
#pragma unroll
    for (int ks = 0; ks < 2; ++ks) {
      const float* pr = &Pf[prow * 72 + ks * 32 + g * 8];
      f4v r0 = *(const f4v*)pr;
      f4v r1 = *(const f4v*)(pr + 4);
      union { unsigned u[4]; s8v s; } pc;
      pc.u[0] = cvt_pk(r0[0], r0[1]);
      pc.u[1] = cvt_pk(r0[2], r0[3]);
      pc.u[2] = cvt_pk(r1[0], r1[1]);
      pc.u[3] = cvt_pk(r1[2], r1[3]);
      s8v pa = pc.s;
#pragma unroll
      for (int n4 = 0; n4 < 4; ++n4) {
        const u16* vr = Vl + (n4 * 16 + l) * 64;
        s8v bvv = *(const s8v*)(vr + ((ks * 4 + g) ^ lx) * 8);
        cacc[n4] = MFMA16(pa, bvv, cacc[n4]);
      }
    }
    __syncthreads();   // B: all waves' P in Pf; K/V reads done
    // store phase: 4 rounds x (16 rows x 256B contiguous per row)
#pragma unroll
    for (int r4 = 0; r4 < 4; ++r4) {
      const int rho = r4 * 16 + st_r;
      f4v pv_ = *(const f4v*)&Pf[rho * 72 + st_c];
      *(f4v*)(attn_h + (size_t)(qt * 64 + rho) * TSEQ + col0 + st_c) = pv_;
    }
  }
  // write ctx (flat layout == (B,T,D) row-major); C row = q-row = g*4+r
#pragma unroll
  for (int n4 = 0; n4 < 4; ++n4)
#pragma unroll
    for (int r = 0; r < 4; ++r)
      ctx[(size_t)hb * HB_ELEMS + (size_t)(row0 + g * 4 + r) * 64 + n4 * 16 + l] =
          cacc[n4][r];
}

// ---------------- residual + LayerNorm ----------------
__global__ void ln_kernel(const float* __restrict__ q, const float* __restrict__ ctx,
                          const float* __restrict__ gam, const float* __restrict__ bet,
                          float* __restrict__ out) {
  const int row = blockIdx.x;
  const int tid = threadIdx.x;
  const float* qr = q + (size_t)row * 1024;
  const float* cr = ctx + (size_t)row * 1024;
  float4 xq = *(const float4*)(qr + tid * 4);
  float4 xc = *(const float4*)(cr + tid * 4);
  float x0 = xq.x + xc.x, x1 = xq.y + xc.y, x2 = xq.z + xc.z, x3 = xq.w + xc.w;
  float s1 = x0 + x1 + x2 + x3;
  float s2 = x0 * x0 + x1 * x1 + x2 * x2 + x3 * x3;
#pragma unroll
  for (int off = 1; off < 64; off <<= 1) {
    s1 += __shfl_xor(s1, off);
    s2 += __shfl_xor(s2, off);
  }
  __shared__ float ra[4], rb[4];
  int w = tid >> 6, lane = tid & 63;
  if (lane == 0) { ra[w] = s1; rb[w] = s2; }
  __syncthreads();
  s1 = ra[0] + ra[1] + ra[2] + ra[3];
  s2 = rb[0] + rb[1] + rb[2] + rb[3];
  float mu = s1 * (1.0f / 1024.0f);
  float var = s2 * (1.0f / 1024.0f) - mu * mu;
  float rstd = rsqrtf(var + 1e-5f);
  float4 gv = *(const float4*)(gam + tid * 4);
  float4 bv = *(const float4*)(bet + tid * 4);
  float4 o;
  o.x = (x0 - mu) * rstd * gv.x + bv.x;
  o.y = (x1 - mu) * rstd * gv.y + bv.y;
  o.z = (x2 - mu) * rstd * gv.z + bv.z;
  o.w = (x3 - mu) * rstd * gv.w + bv.w;
  *(float4*)(out + (size_t)row * 1024 + tid * 4) = o;
}

extern "C" void kernel_launch(void* const* d_in, const int* in_sizes, int n_in,
                              void* d_out, int out_size, void* d_ws, size_t ws_size,
                              hipStream_t stream) {
  const float* q    = (const float*)d_in[0];
  const float* k    = (const float*)d_in[1];
  const float* v    = (const float*)d_in[2];
  const float* wq   = (const float*)d_in[3];
  const float* bq   = (const float*)d_in[4];
  const float* wk   = (const float*)d_in[5];
  const float* bk   = (const float*)d_in[6];
  const float* wv   = (const float*)d_in[7];
  const float* bv   = (const float*)d_in[8];
  const float* ln_g = (const float*)d_in[9];
  const float* ln_b = (const float*)d_in[10];

  char* ws = (char*)d_ws;
  u16* qp   = (u16*)(ws + 31457280);   // 3 x 8 MiB   bf16 projections (qp,kp,vp)
  u16* vT   = (u16*)(ws + 56623104);   // 8 MiB       per-head transposed V
  float* ctx = (float*)(ws + 65011712); // 16 MiB     fp32 context

  float* out  = (float*)d_out;
  float* attn = out + 4194304;

  proj_gemm<<<dim3(8, 32, 3), 256, 0, stream>>>(q, k, v, wq, wk, wv,
                                                bq, bk, bv, qp);

  vtrans<<<dim3(32, 32), 256, 0, stream>>>(qp + 8388608, vT);

  attn_fused<<<dim3(32, 32), 256, 0, stream>>>(qp, qp + 4194304, vT, attn, ctx);

  ln_kernel<<<4096, 256, 0, stream>>>(q, ctx, ln_g, ln_b, out);
}

// Round 14
// 232.409 us; speedup vs baseline: 1.0790x; 1.0790x over previous
//
#include <hip/hip_runtime.h>

typedef unsigned short u16;
typedef __attribute__((ext_vector_type(8))) short s8v;   // 8 x bf16 (4 VGPR)
typedef __attribute__((ext_vector_type(4))) float f4v;   // MFMA accum

#define MFMA16(a, b, c) __builtin_amdgcn_mfma_f32_16x16x32_bf16(a, b, c, 0, 0, 0)

#define TSEQ 2048
#define NTOK 4096          // B*T
#define HEADS 32           // H*B
#define HB_ELEMS 131072    // T*dh elems per head block

__device__ __forceinline__ unsigned cvt_pk(float lo, float hi) {
  unsigned r;
  asm("v_cvt_pk_bf16_f32 %0, %1, %2" : "=v"(r) : "v"(lo), "v"(hi));
  return r;
}

__device__ __forceinline__ void gl_lds16(const u16* g, u16* l) {
  __builtin_amdgcn_global_load_lds(
      (const __attribute__((address_space(1))) void*)g,
      (__attribute__((address_space(3))) void*)l, 16, 0, 0);
}

// ---------------- fused fp32 -> bf16 convert (all 6 tensors, one launch) -----
__global__ void cvt_all(const float* __restrict__ q, const float* __restrict__ k,
                        const float* __restrict__ v, const float* __restrict__ wq,
                        const float* __restrict__ wk, const float* __restrict__ wv,
                        u16* __restrict__ dst) {
  int i = (blockIdx.x * blockDim.x + threadIdx.x) * 4;
  const float* src; int off;
  if (i < 12582912) {
    int s = i >> 22; src = (s == 0) ? q : ((s == 1) ? k : v); off = i & 4194303;
  } else {
    int j = i - 12582912;
    int s = j >> 20; src = (s == 0) ? wq : ((s == 1) ? wk : wv); off = j & 1048575;
  }
  float4 val = *(const float4*)(src + off);
  uint2 o;
  o.x = cvt_pk(val.x, val.y);
  o.y = cvt_pk(val.z, val.w);
  *(uint2*)(dst + i) = o;
}

// ---------------- projection GEMM: C = A(4096x1024) * W(1024x1024)^T + bias ----
// m97-structure (128^2 tile, width-16 global_load_lds, bf16x8 ds_read).
// __launch_bounds__(256,3): force <=170 VGPR so 3 blocks/CU fit (m97's
// measured occupancy); (256,2) let regalloc float and capped at 2 blocks/CU.
__launch_bounds__(256, 3)
__global__ void proj_gemm(const u16* __restrict__ Aall, const u16* __restrict__ Wall,
                          const float* __restrict__ bqp, const float* __restrict__ bkp,
                          const float* __restrict__ bvp, u16* __restrict__ Call) {
  const int z = blockIdx.z;
  const u16* A = Aall + (size_t)z * 4194304;
  const u16* W = Wall + (size_t)z * 1048576;
  u16* C = Call + (size_t)z * 4194304;
  const float* bias = (z == 0) ? bqp : ((z == 1) ? bkp : bvp);

  __shared__ __align__(16) u16 SH[17408];   // As[0..8K) Bs[8K..16K); T[128][136]
  u16* As = SH;
  u16* Bs = SH + 8192;

  const int tid = threadIdx.x;
  const int w = tid >> 6, lane = tid & 63, g = lane >> 4, l = lane & 15;
  const int wr = w >> 1, wc = w & 1;
  const int tr = blockIdx.y * 128, tc = blockIdx.x * 128;

  const int srow = tid >> 3;        // 0..31  (staging row within 32-row chunk)
  const int scol = (tid & 7) * 8;   // elem col within 64

  f4v acc[4][4] = {};

  for (int kt = 0; kt < 1024; kt += 64) {
#pragma unroll
    for (int c4 = 0; c4 < 4; ++c4) {
      gl_lds16(A + (size_t)(tr + c4 * 32 + srow) * 1024 + kt + scol,
               As + c4 * 2048 + tid * 8);
      gl_lds16(W + (size_t)(tc + c4 * 32 + srow) * 1024 + kt + scol,
               Bs + c4 * 2048 + tid * 8);
    }
    __syncthreads();
#pragma unroll
    for (int ks = 0; ks < 2; ++ks) {
      s8v a[4], bb[4];
#pragma unroll
      for (int m = 0; m < 4; ++m)
        a[m] = *(const s8v*)(As + (wr * 64 + m * 16 + l) * 64 + ks * 32 + g * 8);
#pragma unroll
      for (int n = 0; n < 4; ++n)
        bb[n] = *(const s8v*)(Bs + (wc * 64 + n * 16 + l) * 64 + ks * 32 + g * 8);
#pragma unroll
      for (int m = 0; m < 4; ++m)
#pragma unroll
        for (int n = 0; n < 4; ++n)
          acc[m][n] = MFMA16(a[m], bb[n], acc[m][n]);
    }
    __syncthreads();
  }
  // ---- epilogue: bias + bf16 pack into LDS tile T[t 128][d 136], then
  // coalesced 16B global stores. (Loop's trailing barrier makes SH reuse safe.)
  u16* T = SH;
#pragma unroll
  for (int m = 0; m < 4; ++m)
#pragma unroll
    for (int n = 0; n < 4; ++n) {
      int d = wc * 64 + n * 16 + l;
      float bv = bias[tc + d];
      unsigned c01 = cvt_pk(acc[m][n][0] + bv, acc[m][n][1] + bv);
      unsigned c23 = cvt_pk(acc[m][n][2] + bv, acc[m][n][3] + bv);
      int t0 = wr * 64 + m * 16 + g * 4;
      T[(t0 + 0) * 136 + d] = (u16)c01;
      T[(t0 + 1) * 136 + d] = (u16)(c01 >> 16);
      T[(t0 + 2) * 136 + d] = (u16)c23;
      T[(t0 + 3) * 136 + d] = (u16)(c23 >> 16);
    }
  __syncthreads();
#pragma unroll
  for (int it = 0; it < 8; ++it) {
    int t = it * 16 + (tid >> 4);
    int c8 = (tid & 15) * 8;
    *(s8v*)(C + (size_t)(tr + t) * 1024 + tc + c8) = *(const s8v*)&T[t * 136 + c8];
  }
}

// ---------------- per-head V transpose: vT[hb][d][t] = vp[hb][t][d] ----------
__global__ void vtrans(const u16* __restrict__ vp, u16* __restrict__ vT) {
  const int hb = blockIdx.y;
  const int t0 = blockIdx.x * 64;
  const int tid = threadIdx.x;
  __shared__ u16 tl[64][65];
  const u16* vph = vp + (size_t)hb * HB_ELEMS;
  u16* vth = vT + (size_t)hb * HB_ELEMS;
#pragma unroll
  for (int it = 0; it < 4; ++it) {
    int i = (tid + it * 256) * 4;
    int r = i >> 6, c = i & 63;
    *(ushort4*)&tl[r][c] = *(const ushort4*)(vph + (size_t)(t0 + r) * 64 + c);
  }
  __syncthreads();
#pragma unroll
  for (int it = 0; it < 4; ++it) {
    int i = (tid + it * 256) * 4;
    int d = i >> 6, j = i & 63;
    ushort4 o;
    o.x = tl[j + 0][d]; o.y = tl[j + 1][d]; o.z = tl[j + 2][d]; o.w = tl[j + 3][d];
    *(ushort4*)(vth + (size_t)d * TSEQ + t0 + j) = o;
  }
}

// ---------------- fused attention: LDS-staged K/V, swapped-QK^T --------------
// grid: 1024 blocks (32 qtiles x 32 heads, XCD-swizzled); 4 waves x 16 q-rows.
// Pass 1: 256-key rounds. Pass 2: 64-key rounds; P tile kept in fp32 LDS and
// flushed by a dedicated store phase (16 rows x 256B contiguous per instr).
// Column-window rotation spreads concurrent blocks across HBM channels.
__launch_bounds__(256, 4)
__global__ void attn_fused(const u16* __restrict__ qp, const u16* __restrict__ kp,
                           const u16* __restrict__ vT, float* __restrict__ attn,
                           float* __restrict__ ctx) {
  // XCD-bijective swizzle: all 32 q-tiles of a head share (hw & 7) -> same XCD
  const int hw = blockIdx.x + (blockIdx.y << 5);
  const int hb = (hw & 7) + ((hw >> 8) << 3);
  const int qt = (hw >> 3) & 31;

  const int tid = threadIdx.x;
  const int w = tid >> 6, lane = tid & 63, g = lane >> 4, l = lane & 15;
  const int lx = l & 7;

  const u16* qh = qp + (size_t)hb * HB_ELEMS;
  const u16* kh = kp + (size_t)hb * HB_ELEMS;
  const u16* vh = vT + (size_t)hb * HB_ELEMS;

  // pass1: K[256][64] (32KB). pass2: Kl 8KB | Vl 8KB | Pf[64][72] f32 18KB.
  __shared__ __align__(16) u16 SH[17408];

  const int row0 = qt * 64 + w * 16;              // wave's 16 q-rows
  const float scale = 0.125f;                     // dh^-0.5

  // staging geometry: thread t covers rows (t>>3)+{0,32,..}, 16B chunk t&7
  const int srow = tid >> 3;
  const int swc = ((tid & 7) ^ (srow & 7)) * 8;   // swizzled source col (elems)

  // Q as B-operand fragment: lane (g,l) holds Q[row0+l][ks*32+g*8 .. +8)
  s8v qf0 = *(const s8v*)(qh + (size_t)(row0 + l) * 64 + g * 8);
  s8v qf1 = *(const s8v*)(qh + (size_t)(row0 + l) * 64 + 32 + g * 8);

  // ---- pass 1: row sums of exp(score); swapped mfma(K,Q) => C col = q-row l
  float sum = 0.0f;
  for (int kt4 = 0; kt4 < 8; ++kt4) {
    const int c0 = kt4 * 256;
#pragma unroll
    for (int c8 = 0; c8 < 8; ++c8)
      gl_lds16(kh + (size_t)(c0 + c8 * 32 + srow) * 64 + swc,
               SH + c8 * 2048 + tid * 8);
    __syncthreads();
#pragma unroll
    for (int q4 = 0; q4 < 4; ++q4) {
#pragma unroll
      for (int n = 0; n < 4; ++n) {
        const u16* kr = SH + q4 * 4096 + (n * 16 + l) * 64;
        s8v b0 = *(const s8v*)(kr + (g ^ lx) * 8);
        s8v b1 = *(const s8v*)(kr + ((4 + g) ^ lx) * 8);
        f4v s = {};
        s = MFMA16(b0, qf0, s);
        s = MFMA16(b1, qf1, s);
        sum += __expf(s[0] * scale) + __expf(s[1] * scale)
             + __expf(s[2] * scale) + __expf(s[3] * scale);
      }
    }
    __syncthreads();
  }
  // reduce across the 4 g-groups holding the same q-row l
  sum += __shfl_xor(sum, 16);
  sum += __shfl_xor(sum, 32);
  const float inv = 1.0f / sum;

  // ---- pass 2: recompute, P -> fp32 LDS, PV, then coalesced store phase ----
  u16* Kl = SH;                       // [64][64] bf16 swizzled (8 KB)
  u16* Vl = SH + 4096;                // [64][64] bf16 swizzled (8 KB)
  float* Pf = (float*)(SH + 8192);    // [64][72] f32 P tile (18 KB)

  f4v cacc[4] = {};
  float* attn_h = attn + (size_t)hb * TSEQ * TSEQ;
  const int kt0 = (qt + ((hw >> 8) << 3)) & 31;   // column-window rotation
  const int prow = w * 16 + l;                    // this lane's P row
  const int st_r = tid >> 4;                      // store-phase row within 16
  const int st_c = (tid & 15) * 4;                // store-phase float col
  for (int i = 0; i < 32; ++i) {
    const int kt = (i + kt0) & 31;
    const int col0 = kt * 64;
    gl_lds16(kh + (size_t)(col0 + srow) * 64 + swc, Kl + tid * 8);
    gl_lds16(kh + (size_t)(col0 + 32 + srow) * 64 + swc, Kl + 2048 + tid * 8);
    gl_lds16(vh + (size_t)srow * TSEQ + col0 + swc, Vl + tid * 8);
    gl_lds16(vh + (size_t)(srow + 32) * TSEQ + col0 + swc, Vl + 2048 + tid * 8);
    __syncthreads();   // A: stage complete; prev store-phase Pf reads done
#pragma unroll
    for (int n = 0; n < 4; ++n) {
      const u16* kr = Kl + (n * 16 + l) * 64;
      s8v b0 = *(const s8v*)(kr + (g ^ lx) * 8);
      s8v b1 = *(const s8v*)(kr + ((4 + g) ^ lx) * 8);
      f4v s = {};
      s = MFMA16(b0, qf0, s);
      s = MFMA16(b1, qf1, s);
      f4v p;
#pragma unroll
      for (int r = 0; r < 4; ++r) p[r] = __expf(s[r] * scale) * inv;
      // P[q-row l][keys n*16+g*4 .. +4) for this wave
      *(f4v*)&Pf[prow * 72 + n * 16 + g * 4] = p;
    }
    // PV for this 64-key tile: read wave-local P rows, pack bf16 on the fly
#pragma unroll
    for (int ks = 0; ks < 2; ++ks) {
      const float* pr = &Pf[prow * 72 + ks * 32 + g * 8];
      f4v r0 = *(const f4v*)pr;
      f4v r1 = *(const f4v*)(pr + 4);
      union { unsigned u[4]; s8v s; } pc;
      pc.u[0] = cvt_pk(r0[0], r0[1]);
      pc.u[1] = cvt_pk(r0[2], r0[3]);
      pc.u[2] = cvt_pk(r1[0], r1[1]);
      pc.u[3] = cvt_pk(r1[2], r1[3]);
      s8v pa = pc.s;
#pragma unroll
      for (int n4 = 0; n4 < 4; ++n4) {
        const u16* vr = Vl + (n4 * 16 + l) * 64;
        s8v bvv = *(const s8v*)(vr + ((ks * 4 + g) ^ lx) * 8);
        cacc[n4] = MFMA16(pa, bvv, cacc[n4]);
      }
    }
    __syncthreads();   // B: all waves' P in Pf; K/V reads done
    // store phase: 4 rounds x (16 rows x 256B contiguous per row)
#pragma unroll
    for (int r4 = 0; r4 < 4; ++r4) {
      const int rho = r4 * 16 + st_r;
      f4v pv_ = *(const f4v*)&Pf[rho * 72 + st_c];
      *(f4v*)(attn_h + (size_t)(qt * 64 + rho) * TSEQ + col0 + st_c) = pv_;
    }
  }
  // write ctx (flat layout == (B,T,D) row-major); C row = q-row = g*4+r
#pragma unroll
  for (int n4 = 0; n4 < 4; ++n4)
#pragma unroll
    for (int r = 0; r < 4; ++r)
      ctx[(size_t)hb * HB_ELEMS + (size_t)(row0 + g * 4 + r) * 64 + n4 * 16 + l] =
          cacc[n4][r];
}

// ---------------- residual + LayerNorm ----------------
__global__ void ln_kernel(const float* __restrict__ q, const float* __restrict__ ctx,
                          const float* __restrict__ gam, const float* __restrict__ bet,
                          float* __restrict__ out) {
  const int row = blockIdx.x;
  const int tid = threadIdx.x;
  const float* qr = q + (size_t)row * 1024;
  const float* cr = ctx + (size_t)row * 1024;
  float4 xq = *(const float4*)(qr + tid * 4);
  float4 xc = *(const float4*)(cr + tid * 4);
  float x0 = xq.x + xc.x, x1 = xq.y + xc.y, x2 = xq.z + xc.z, x3 = xq.w + xc.w;
  float s1 = x0 + x1 + x2 + x3;
  float s2 = x0 * x0 + x1 * x1 + x2 * x2 + x3 * x3;
#pragma unroll
  for (int off = 1; off < 64; off <<= 1) {
    s1 += __shfl_xor(s1, off);
    s2 += __shfl_xor(s2, off);
  }
  __shared__ float ra[4], rb[4];
  int w = tid >> 6, lane = tid & 63;
  if (lane == 0) { ra[w] = s1; rb[w] = s2; }
  __syncthreads();
  s1 = ra[0] + ra[1] + ra[2] + ra[3];
  s2 = rb[0] + rb[1] + rb[2] + rb[3];
  float mu = s1 * (1.0f / 1024.0f);
  float var = s2 * (1.0f / 1024.0f) - mu * mu;
  float rstd = rsqrtf(var + 1e-5f);
  float4 gv = *(const float4*)(gam + tid * 4);
  float4 bv = *(const float4*)(bet + tid * 4);
  float4 o;
  o.x = (x0 - mu) * rstd * gv.x + bv.x;
  o.y = (x1 - mu) * rstd * gv.y + bv.y;
  o.z = (x2 - mu) * rstd * gv.z + bv.z;
  o.w = (x3 - mu) * rstd * gv.w + bv.w;
  *(float4*)(out + (size_t)row * 1024 + tid * 4) = o;
}

extern "C" void kernel_launch(void* const* d_in, const int* in_sizes, int n_in,
                              void* d_out, int out_size, void* d_ws, size_t ws_size,
                              hipStream_t stream) {
  const float* q    = (const float*)d_in[0];
  const float* k    = (const float*)d_in[1];
  const float* v    = (const float*)d_in[2];
  const float* wq   = (const float*)d_in[3];
  const float* bq   = (const float*)d_in[4];
  const float* wk   = (const float*)d_in[5];
  const float* bk   = (const float*)d_in[6];
  const float* wv   = (const float*)d_in[7];
  const float* bv   = (const float*)d_in[8];
  const float* ln_g = (const float*)d_in[9];
  const float* ln_b = (const float*)d_in[10];

  char* ws = (char*)d_ws;
  u16* qbf  = (u16*)(ws);              // 3 x 8 MiB   bf16 inputs (q,k,v)
  u16* wbf  = (u16*)(ws + 25165824);   // 3 x 2 MiB   bf16 weights (contig w/ qbf)
  u16* qp   = (u16*)(ws + 31457280);   // 3 x 8 MiB   bf16 projections (qp,kp,vp)
  u16* vT   = (u16*)(ws + 56623104);   // 8 MiB       per-head transposed V
  float* ctx = (float*)(ws + 65011712); // 16 MiB     fp32 context

  float* out  = (float*)d_out;
  float* attn = out + 4194304;

  cvt_all<<<15360, 256, 0, stream>>>(q, k, v, wq, wk, wv, qbf);

  proj_gemm<<<dim3(8, 32, 3), 256, 0, stream>>>(qbf, wbf, bq, bk, bv, qp);

  vtrans<<<dim3(32, 32), 256, 0, stream>>>(qp + 8388608, vT);

  attn_fused<<<dim3(32, 32), 256, 0, stream>>>(qp, qp + 4194304, vT, attn, ctx);

  ln_kernel<<<4096, 256, 0, stream>>>(q, ctx, ln_g, ln_b, out);
}

// Round 16
// 222.486 us; speedup vs baseline: 1.1271x; 1.0446x over previous
//
#include <hip/hip_runtime.h>

typedef unsigned short u16;
typedef __attribute__((ext_vector_type(8))) short s8v;   // 8 x bf16 (4 VGPR)
typedef __attribute__((ext_vector_type(4))) float f4v;   // MFMA accum

#define MFMA16(a, b, c) __builtin_amdgcn_mfma_f32_16x16x32_bf16(a, b, c, 0, 0, 0)

#define TSEQ 2048
#define NTOK 4096          // B*T
#define HEADS 32           // H*B
#define HB_ELEMS 131072    // T*dh elems per head block

__device__ __forceinline__ unsigned cvt_pk(float lo, float hi) {
  unsigned r;
  asm("v_cvt_pk_bf16_f32 %0, %1, %2" : "=v"(r) : "v"(lo), "v"(hi));
  return r;
}

__device__ __forceinline__ void gl_lds16(const u16* g, u16* l) {
  __builtin_amdgcn_global_load_lds(
      (const __attribute__((address_space(1))) void*)g,
      (__attribute__((address_space(3))) void*)l, 16, 0, 0);
}

// ---------------- fused fp32 -> bf16 convert (all 6 tensors, one launch) -----
__global__ void cvt_all(const float* __restrict__ q, const float* __restrict__ k,
                        const float* __restrict__ v, const float* __restrict__ wq,
                        const float* __restrict__ wk, const float* __restrict__ wv,
                        u16* __restrict__ dst) {
  int i = (blockIdx.x * blockDim.x + threadIdx.x) * 4;
  const float* src; int off;
  if (i < 12582912) {
    int s = i >> 22; src = (s == 0) ? q : ((s == 1) ? k : v); off = i & 4194303;
  } else {
    int j = i - 12582912;
    int s = j >> 20; src = (s == 0) ? wq : ((s == 1) ? wk : wv); off = j & 1048575;
  }
  float4 val = *(const float4*)(src + off);
  uint2 o;
  o.x = cvt_pk(val.x, val.y);
  o.y = cvt_pk(val.z, val.w);
  *(uint2*)(dst + i) = o;
}

// ---------------- projection GEMM: C = A(4096x1024) * W(1024x1024)^T + bias ----
__launch_bounds__(256, 3)
__global__ void proj_gemm(const u16* __restrict__ Aall, const u16* __restrict__ Wall,
                          const float* __restrict__ bqp, const float* __restrict__ bkp,
                          const float* __restrict__ bvp, u16* __restrict__ Call) {
  const int z = blockIdx.z;
  const u16* A = Aall + (size_t)z * 4194304;
  const u16* W = Wall + (size_t)z * 1048576;
  u16* C = Call + (size_t)z * 4194304;
  const float* bias = (z == 0) ? bqp : ((z == 1) ? bkp : bvp);

  __shared__ __align__(16) u16 SH[17408];   // As[0..8K) Bs[8K..16K); T[128][136]
  u16* As = SH;
  u16* Bs = SH + 8192;

  const int tid = threadIdx.x;
  const int w = tid >> 6, lane = tid & 63, g = lane >> 4, l = lane & 15;
  const int wr = w >> 1, wc = w & 1;
  const int tr = blockIdx.y * 128, tc = blockIdx.x * 128;

  const int srow = tid >> 3;        // 0..31  (staging row within 32-row chunk)
  const int scol = (tid & 7) * 8;   // elem col within 64

  f4v acc[4][4] = {};

  for (int kt = 0; kt < 1024; kt += 64) {
#pragma unroll
    for (int c4 = 0; c4 < 4; ++c4) {
      gl_lds16(A + (size_t)(tr + c4 * 32 + srow) * 1024 + kt + scol,
               As + c4 * 2048 + tid * 8);
      gl_lds16(W + (size_t)(tc + c4 * 32 + srow) * 1024 + kt + scol,
               Bs + c4 * 2048 + tid * 8);
    }
    __syncthreads();
#pragma unroll
    for (int ks = 0; ks < 2; ++ks) {
      s8v a[4], bb[4];
#pragma unroll
      for (int m = 0; m < 4; ++m)
        a[m] = *(const s8v*)(As + (wr * 64 + m * 16 + l) * 64 + ks * 32 + g * 8);
#pragma unroll
      for (int n = 0; n < 4; ++n)
        bb[n] = *(const s8v*)(Bs + (wc * 64 + n * 16 + l) * 64 + ks * 32 + g * 8);
#pragma unroll
      for (int m = 0; m < 4; ++m)
#pragma unroll
        for (int n = 0; n < 4; ++n)
          acc[m][n] = MFMA16(a[m], bb[n], acc[m][n]);
    }
    __syncthreads();
  }
  // ---- epilogue: bias + bf16 pack into LDS tile T[t 128][d 136], then
  // coalesced 16B global stores.
  u16* T = SH;
#pragma unroll
  for (int m = 0; m < 4; ++m)
#pragma unroll
    for (int n = 0; n < 4; ++n) {
      int d = wc * 64 + n * 16 + l;
      float bv = bias[tc + d];
      unsigned c01 = cvt_pk(acc[m][n][0] + bv, acc[m][n][1] + bv);
      unsigned c23 = cvt_pk(acc[m][n][2] + bv, acc[m][n][3] + bv);
      int t0 = wr * 64 + m * 16 + g * 4;
      T[(t0 + 0) * 136 + d] = (u16)c01;
      T[(t0 + 1) * 136 + d] = (u16)(c01 >> 16);
      T[(t0 + 2) * 136 + d] = (u16)c23;
      T[(t0 + 3) * 136 + d] = (u16)(c23 >> 16);
    }
  __syncthreads();
#pragma unroll
  for (int it = 0; it < 8; ++it) {
    int t = it * 16 + (tid >> 4);
    int c8 = (tid & 15) * 8;
    *(s8v*)(C + (size_t)(tr + t) * 1024 + tc + c8) = *(const s8v*)&T[t * 136 + c8];
  }
}

// ---------------- per-head V transpose: vT[hb][d][t] = vp[hb][t][d] ----------
__global__ void vtrans(const u16* __restrict__ vp, u16* __restrict__ vT) {
  const int hb = blockIdx.y;
  const int t0 = blockIdx.x * 64;
  const int tid = threadIdx.x;
  __shared__ u16 tl[64][65];
  const u16* vph = vp + (size_t)hb * HB_ELEMS;
  u16* vth = vT + (size_t)hb * HB_ELEMS;
#pragma unroll
  for (int it = 0; it < 4; ++it) {
    int i = (tid + it * 256) * 4;
    int r = i >> 6, c = i & 63;
    *(ushort4*)&tl[r][c] = *(const ushort4*)(vph + (size_t)(t0 + r) * 64 + c);
  }
  __syncthreads();
#pragma unroll
  for (int it = 0; it < 4; ++it) {
    int i = (tid + it * 256) * 4;
    int d = i >> 6, j = i & 63;
    ushort4 o;
    o.x = tl[j + 0][d]; o.y = tl[j + 1][d]; o.z = tl[j + 2][d]; o.w = tl[j + 3][d];
    *(ushort4*)(vth + (size_t)d * TSEQ + t0 + j) = o;
  }
}

// ---------------- fused attention: 128-row q-tiles, 8 waves -----------------
// grid: 512 blocks (16 qtiles x 32 heads, XCD-swizzled); 8 waves x 16 q-rows.
// Sync pattern is EXACTLY R12's proven {stage; A; compute; B; store}: the
// cooperative store phase runs after barrier B (all Pf writes visible).
// 128-row tile halves pass-2 staging per output and halves pass-1 blocks.
// LDS 52KB -> 3 blocks/CU (24 waves/CU).
__launch_bounds__(512, 2)
__global__ void attn_fused(const u16* __restrict__ qp, const u16* __restrict__ kp,
                           const u16* __restrict__ vT, float* __restrict__ attn,
                           float* __restrict__ ctx) {
  // XCD-bijective swizzle: all 16 q-tiles of a head share (hw & 7) -> same XCD
  const int hw = blockIdx.x + (blockIdx.y << 4);
  const int hb = (hw & 7) + ((hw >> 7) << 3);
  const int qt = (hw >> 3) & 15;

  const int tid = threadIdx.x;                    // 0..511
  const int w = tid >> 6, lane = tid & 63, g = lane >> 4, l = lane & 15;
  const int lx = l & 7;

  const u16* qh = qp + (size_t)hb * HB_ELEMS;
  const u16* kh = kp + (size_t)hb * HB_ELEMS;
  const u16* vh = vT + (size_t)hb * HB_ELEMS;

  // pass1: K[256][64] (32KB). pass2: Kl 8KB | Vl 8KB | Pf[128][72] f32 36.9KB.
  __shared__ __align__(16) u16 SH[26624];         // 52 KB

  const int row0 = qt * 128 + w * 16;             // wave's 16 q-rows
  const float scale = 0.125f;                     // dh^-0.5

  // staging geometry: thread t covers row (t>>3), 16B chunk t&7
  const int srow = tid >> 3;                      // 0..63
  const int swc = ((tid & 7) ^ (srow & 7)) * 8;   // swizzled source col (elems)

  // Q as B-operand fragment: lane (g,l) holds Q[row0+l][ks*32+g*8 .. +8)
  s8v qf0 = *(const s8v*)(qh + (size_t)(row0 + l) * 64 + g * 8);
  s8v qf1 = *(const s8v*)(qh + (size_t)(row0 + l) * 64 + 32 + g * 8);

  // ---- pass 1: row sums of exp(score); swapped mfma(K,Q) => C col = q-row l
  float sum = 0.0f;
  for (int kt4 = 0; kt4 < 8; ++kt4) {
    const int c0 = kt4 * 256;
#pragma unroll
    for (int c4 = 0; c4 < 4; ++c4)
      gl_lds16(kh + (size_t)(c0 + c4 * 64 + srow) * 64 + swc,
               SH + c4 * 4096 + tid * 8);
    __syncthreads();
#pragma unroll
    for (int q4 = 0; q4 < 4; ++q4) {
#pragma unroll
      for (int n = 0; n < 4; ++n) {
        const u16* kr = SH + q4 * 4096 + (n * 16 + l) * 64;
        s8v b0 = *(const s8v*)(kr + (g ^ lx) * 8);
        s8v b1 = *(const s8v*)(kr + ((4 + g) ^ lx) * 8);
        f4v s = {};
        s = MFMA16(b0, qf0, s);
        s = MFMA16(b1, qf1, s);
        sum += __expf(s[0] * scale) + __expf(s[1] * scale)
             + __expf(s[2] * scale) + __expf(s[3] * scale);
      }
    }
    __syncthreads();
  }
  // reduce across the 4 g-groups holding the same q-row l
  sum += __shfl_xor(sum, 16);
  sum += __shfl_xor(sum, 32);
  const float inv = 1.0f / sum;

  // ---- pass 2: recompute, P -> fp32 LDS, PV, post-barrier coalesced store --
  u16* Kl = SH;                       // [64][64] bf16 swizzled (8 KB)
  u16* Vl = SH + 4096;                // [64][64] bf16 swizzled (8 KB)
  float* Pf = (float*)(SH + 8192);    // [128][72] f32 P tile (36.9 KB)

  f4v cacc[4] = {};
  float* attn_h = attn + (size_t)hb * TSEQ * TSEQ;
  const int kt0 = (qt * 2 + ((hw >> 7) << 3)) & 31;  // column-window rotation
  const int prow = w * 16 + l;                    // this lane's P row
  const int st_r = tid >> 4;                      // store-phase row 0..31
  const int st_c = (tid & 15) * 4;                // store-phase float col
  for (int i = 0; i < 32; ++i) {
    const int kt = (i + kt0) & 31;
    const int col0 = kt * 64;
    gl_lds16(kh + (size_t)(col0 + srow) * 64 + swc, Kl + tid * 8);
    gl_lds16(vh + (size_t)srow * TSEQ + col0 + swc, Vl + tid * 8);
    __syncthreads();   // A: stage complete; prev store-phase Pf reads done
#pragma unroll
    for (int n = 0; n < 4; ++n) {
      const u16* kr = Kl + (n * 16 + l) * 64;
      s8v b0 = *(const s8v*)(kr + (g ^ lx) * 8);
      s8v b1 = *(const s8v*)(kr + ((4 + g) ^ lx) * 8);
      f4v s = {};
      s = MFMA16(b0, qf0, s);
      s = MFMA16(b1, qf1, s);
      f4v p;
#pragma unroll
      for (int r = 0; r < 4; ++r) p[r] = __expf(s[r] * scale) * inv;
      // P[q-row l][keys n*16+g*4 .. +4) for this wave
      *(f4v*)&Pf[prow * 72 + n * 16 + g * 4] = p;
    }
    // PV for this 64-key tile: read wave-local P rows, pack bf16 on the fly
#pragma unroll
    for (int ks = 0; ks < 2; ++ks) {
      const float* pr = &Pf[prow * 72 + ks * 32 + g * 8];
      f4v r0 = *(const f4v*)pr;
      f4v r1 = *(const f4v*)(pr + 4);
      union { unsigned u[4]; s8v s; } pc;
      pc.u[0] = cvt_pk(r0[0], r0[1]);
      pc.u[1] = cvt_pk(r0[2], r0[3]);
      pc.u[2] = cvt_pk(r1[0], r1[1]);
      pc.u[3] = cvt_pk(r1[2], r1[3]);
      s8v pa = pc.s;
#pragma unroll
      for (int n4 = 0; n4 < 4; ++n4) {
        const u16* vr = Vl + (n4 * 16 + l) * 64;
        s8v bvv = *(const s8v*)(vr + ((ks * 4 + g) ^ lx) * 8);
        cacc[n4] = MFMA16(pa, bvv, cacc[n4]);
      }
    }
    __syncthreads();   // B: all waves' P visible in Pf; K/V reads done
    // store phase: 4 rounds x (32 rows x 256B contiguous per row)
#pragma unroll
    for (int r4 = 0; r4 < 4; ++r4) {
      const int rho = r4 * 32 + st_r;
      f4v pv_ = *(const f4v*)&Pf[rho * 72 + st_c];
      *(f4v*)(attn_h + (size_t)(qt * 128 + rho) * TSEQ + col0 + st_c) = pv_;
    }
  }
  // write ctx (flat layout == (B,T,D) row-major); C row = q-row = g*4+r
#pragma unroll
  for (int n4 = 0; n4 < 4; ++n4)
#pragma unroll
    for (int r = 0; r < 4; ++r)
      ctx[(size_t)hb * HB_ELEMS + (size_t)(row0 + g * 4 + r) * 64 + n4 * 16 + l] =
          cacc[n4][r];
}

// ---------------- residual + LayerNorm ----------------
__global__ void ln_kernel(const float* __restrict__ q, const float* __restrict__ ctx,
                          const float* __restrict__ gam, const float* __restrict__ bet,
                          float* __restrict__ out) {
  const int row = blockIdx.x;
  const int tid = threadIdx.x;
  const float* qr = q + (size_t)row * 1024;
  const float* cr = ctx + (size_t)row * 1024;
  float4 xq = *(const float4*)(qr + tid * 4);
  float4 xc = *(const float4*)(cr + tid * 4);
  float x0 = xq.x + xc.x, x1 = xq.y + xc.y, x2 = xq.z + xc.z, x3 = xq.w + xc.w;
  float s1 = x0 + x1 + x2 + x3;
  float s2 = x0 * x0 + x1 * x1 + x2 * x2 + x3 * x3;
#pragma unroll
  for (int off = 1; off < 64; off <<= 1) {
    s1 += __shfl_xor(s1, off);
    s2 += __shfl_xor(s2, off);
  }
  __shared__ float ra[4], rb[4];
  int w = tid >> 6, lane = tid & 63;
  if (lane == 0) { ra[w] = s1; rb[w] = s2; }
  __syncthreads();
  s1 = ra[0] + ra[1] + ra[2] + ra[3];
  s2 = rb[0] + rb[1] + rb[2] + rb[3];
  float mu = s1 * (1.0f / 1024.0f);
  float var = s2 * (1.0f / 1024.0f) - mu * mu;
  float rstd = rsqrtf(var + 1e-5f);
  float4 gv = *(const float4*)(gam + tid * 4);
  float4 bv = *(const float4*)(bet + tid * 4);
  float4 o;
  o.x = (x0 - mu) * rstd * gv.x + bv.x;
  o.y = (x1 - mu) * rstd * gv.y + bv.y;
  o.z = (x2 - mu) * rstd * gv.z + bv.z;
  o.w = (x3 - mu) * rstd * gv.w + bv.w;
  *(float4*)(out + (size_t)row * 1024 + tid * 4) = o;
}

extern "C" void kernel_launch(void* const* d_in, const int* in_sizes, int n_in,
                              void* d_out, int out_size, void* d_ws, size_t ws_size,
                              hipStream_t stream) {
  const float* q    = (const float*)d_in[0];
  const float* k    = (const float*)d_in[1];
  const float* v    = (const float*)d_in[2];
  const float* wq   = (const float*)d_in[3];
  const float* bq   = (const float*)d_in[4];
  const float* wk   = (const float*)d_in[5];
  const float* bk   = (const float*)d_in[6];
  const float* wv   = (const float*)d_in[7];
  const float* bv   = (const float*)d_in[8];
  const float* ln_g = (const float*)d_in[9];
  const float* ln_b = (const float*)d_in[10];

  char* ws = (char*)d_ws;
  u16* qbf  = (u16*)(ws);              // 3 x 8 MiB   bf16 inputs (q,k,v)
  u16* wbf  = (u16*)(ws + 25165824);   // 3 x 2 MiB   bf16 weights (contig w/ qbf)
  u16* qp   = (u16*)(ws + 31457280);   // 3 x 8 MiB   bf16 projections (qp,kp,vp)
  u16* vT   = (u16*)(ws + 56623104);   // 8 MiB       per-head transposed V
  float* ctx = (float*)(ws + 65011712); // 16 MiB     fp32 context

  float* out  = (float*)d_out;
  float* attn = out + 4194304;

  cvt_all<<<15360, 256, 0, stream>>>(q, k, v, wq, wk, wv, qbf);

  proj_gemm<<<dim3(8, 32, 3), 256, 0, stream>>>(qbf, wbf, bq, bk, bv, qp);

  vtrans<<<dim3(32, 32), 256, 0, stream>>>(qp + 8388608, vT);

  attn_fused<<<dim3(16, 32), 512, 0, stream>>>(qp, qp + 4194304, vT, attn, ctx);

  ln_kernel<<<4096, 256, 0, stream>>>(q, ctx, ln_g, ln_b, out);
}